// Round 2
// baseline (25.825 us; speedup 1.0000x reference)
//
#include <hip/hip_runtime.h>

// Quanvolution quantum filter, collapsed analytically:
//   per 2x2 patch (t0,t1,t2,t3), with cq = cos(tq):
//     out[0] = c1*c2*c3
//     out[1] = c0*c1
//     out[2] = c0*c1*c2
//     out[3] = c0*c1*c2*c3
// Derivation: product state Ry rotations -> P(bq=1)=sin^2(tq/2); CNOT ring
// permutes basis states so each Z expectation is E[(-1)^{XOR subset}] =
// prod over subset of cos(tq).
//
// One thread handles TWO horizontally-adjacent patches:
//   loads:  float4 (top row, 2 patches) + float4 (bottom row) = 16B/inst
//   stores: 2x float4, 32B contiguous per thread, fully coalesced.
// __cosf -> v_cos_f32 hardware path (~1e-5 err, threshold 2e-2).

#define BATCH 16384
#define PAIRS_PER_IMG 98           // 196 patches / 2
#define TOTAL_PAIRS (BATCH * PAIRS_PER_IMG)

__global__ __launch_bounds__(256) void quanv_kernel(const float* __restrict__ x,
                                                    float* __restrict__ out) {
    int t = blockIdx.x * blockDim.x + threadIdx.x;
    if (t >= TOTAL_PAIRS) return;
    int b = t / PAIRS_PER_IMG;
    int idx = t - b * PAIRS_PER_IMG;   // 0..97
    int r = idx / 7;                   // patch row 0..13
    int cp = idx - r * 7;              // patch-pair col 0..6

    const float* img = x + (size_t)b * 784;
    int base = r * 56 + cp * 4;        // (2r)*28 + (2*(2cp))

    float4 top = *reinterpret_cast<const float4*>(img + base);        // A:t0,t1  B:t0,t1
    float4 bot = *reinterpret_cast<const float4*>(img + base + 28);   // A:t2,t3  B:t2,t3

    float a0 = __cosf(top.x), a1 = __cosf(top.y);
    float a2 = __cosf(bot.x), a3 = __cosf(bot.y);
    float b0 = __cosf(top.z), b1 = __cosf(top.w);
    float b2 = __cosf(bot.z), b3 = __cosf(bot.w);

    float4 oa, ob;
    oa.y = a0 * a1;          // meas1
    oa.z = oa.y * a2;        // meas2
    oa.w = oa.z * a3;        // meas3
    oa.x = a1 * a2 * a3;     // meas0
    ob.y = b0 * b1;
    ob.z = ob.y * b2;
    ob.w = ob.z * b3;
    ob.x = b1 * b2 * b3;

    float* o = out + (size_t)b * 784 + (size_t)(r * 14 + cp * 2) * 4;
    *reinterpret_cast<float4*>(o) = oa;
    *reinterpret_cast<float4*>(o + 4) = ob;
}

extern "C" void kernel_launch(void* const* d_in, const int* in_sizes, int n_in,
                              void* d_out, int out_size, void* d_ws, size_t ws_size,
                              hipStream_t stream) {
    const float* x = (const float*)d_in[0];
    float* out = (float*)d_out;
    int blocks = (TOTAL_PAIRS + 255) / 256;   // 6272
    quanv_kernel<<<blocks, 256, 0, stream>>>(x, out);
}

// Round 3
// 20.975 us; speedup vs baseline: 1.2312x; 1.2312x over previous
//
#include <hip/hip_runtime.h>

// Quanvolution quantum filter, collapsed analytically:
//   per 2x2 patch (t0,t1,t2,t3), with cq = cos(tq):
//     out[0] = c1*c2*c3
//     out[1] = c0*c1
//     out[2] = c0*c1*c2
//     out[3] = c0*c1*c2*c3
// Derivation: product state Ry rotations -> P(bq=1)=sin^2(tq/2); CNOT ring
// permutes basis states so each Z expectation is E[(-1)^{XOR subset}] =
// prod over subset of cos(tq).
//
// R2 post-mortem: pair-per-thread (2x float4 load / 2x float4 store at 32B
// lane stride) regressed vs v1's unit-stride pattern — per-instruction
// cacheline density beats per-lane width here. Keep v1's memory pattern:
//   loads:  2x float2, 8B lane stride, dense
//   store:  1x float4, 16B lane stride, dense
// Only change vs v1: cosf -> __cosf (v_cos_f32 hardware path, ~1e-5 err
// vs 2e-2 threshold; absmax measured unchanged at 0.0039).

#define BATCH 16384
#define PATCHES 196   // 14 x 14
#define TOTAL (BATCH * PATCHES)

__global__ __launch_bounds__(256) void quanv_kernel(const float* __restrict__ x,
                                                    float* __restrict__ out) {
    int t = blockIdx.x * blockDim.x + threadIdx.x;
    if (t >= TOTAL) return;
    int b = t / PATCHES;
    int p = t - b * PATCHES;
    int r = p / 14;
    int c = p - r * 14;

    const float* img = x + (size_t)b * 784;
    int base = r * 56 + c * 2;

    float2 top = *reinterpret_cast<const float2*>(img + base);        // t0, t1
    float2 bot = *reinterpret_cast<const float2*>(img + base + 28);   // t2, t3

    float c0 = __cosf(top.x);
    float c1 = __cosf(top.y);
    float c2 = __cosf(bot.x);
    float c3 = __cosf(bot.y);

    float4 o;
    o.y = c0 * c1;        // meas1
    o.z = o.y * c2;       // meas2
    o.w = o.z * c3;       // meas3
    o.x = c1 * c2 * c3;   // meas0

    *reinterpret_cast<float4*>(out + (size_t)t * 4) = o;
}

extern "C" void kernel_launch(void* const* d_in, const int* in_sizes, int n_in,
                              void* d_out, int out_size, void* d_ws, size_t ws_size,
                              hipStream_t stream) {
    const float* x = (const float*)d_in[0];
    float* out = (float*)d_out;
    int blocks = (TOTAL + 255) / 256;   // 12544
    quanv_kernel<<<blocks, 256, 0, stream>>>(x, out);
}